// Round 2
// baseline (795.981 us; speedup 1.0000x reference)
//
#include <hip/hip_runtime.h>

// CRF log-likelihood. B=256, L=1024, D=126, T=128.
// R5: TWO batches per workgroup (128 blocks x 1024 threads; waves 0-7 =
// batch A, waves 8-15 = batch B). The forward recursion is serial and
// latency-bound (R1 counters: VALUBusy 34%, LDS ~35%, both idle 2/3 of the
// time with only 2 lockstep waves/SIMD). Interleaving two independent
// recursions in one workgroup hides each one's chain latency (ds_read
// ~120cyc, barrier drain) under the other's compute. Per-batch layout is
// unchanged from R4: thread = 4 outputs (j) x 8 inputs (k), 2x
// ds_read_b128 for E, DPP row_ror ring-reduce over 16 lanes, XOR-swizzled
// E, rebase every 4th step, raw lgkmcnt(0)+s_barrier per step. Transitions
// are shared by both batches so per-thread register state is unchanged.

#define LOG2E   1.4426950408889634f
#define LN2     0.6931471805599453f

constexpr int Bc = 256, Lc = 1024, Dc = 126, Tc = 128;
constexpr int CH = 16, CHF = CH * Dc;       // 2016 floats per chunk
constexpr int NCH = Lc / CH;                // 64 chunks

#if __has_builtin(__builtin_amdgcn_exp2f)
#define FEXP2(x) __builtin_amdgcn_exp2f(x)
#else
#define FEXP2(x) exp2f(x)
#endif
#if __has_builtin(__builtin_amdgcn_logf)
#define FLOG2(x) __builtin_amdgcn_logf(x)
#else
#define FLOG2(x) log2f(x)
#endif

// DPP row_ror:N within 16-lane rows (ring-reduce: after ror 1,2,4,8 every
// lane holds the row total).
#if __has_builtin(__builtin_amdgcn_mov_dpp)
#define DPPF(x, ctrl) __int_as_float(__builtin_amdgcn_mov_dpp(__float_as_int(x), (ctrl), 0xF, 0xF, true))
#define ROR1(x) DPPF(x, 0x121)
#define ROR2(x) DPPF(x, 0x122)
#define ROR4(x) DPPF(x, 0x124)
#define ROR8(x) DPPF(x, 0x128)
#else
#define ROR1(x) __shfl_xor((x), 1, 64)
#define ROR2(x) __shfl_xor((x), 2, 64)
#define ROR4(x) __shfl_xor((x), 4, 64)
#define ROR8(x) __shfl_xor((x), 8, 64)
#endif

#define STEP_BARRIER() asm volatile("s_waitcnt lgkmcnt(0)\n\ts_barrier" ::: "memory")

__global__ __launch_bounds__(1024, 1) void crf_fwd_kernel(
    const float* __restrict__ x,      // [B, L, D]
    const float* __restrict__ trans,  // [T, T] row-major
    const int*   __restrict__ x_len,  // [B]
    const int*   __restrict__ tag,    // [B, L]
    float*       __restrict__ out)    // [B]
{
    __shared__ __align__(16) float E[2][2][Tc];      // [half][dbuf][T], swizzled
    __shared__ __align__(16) float Lbuf[2][2][CHF];  // [half][dbuf][chunk], linear
    __shared__ float red[2][12];                     // per-half epilogue reductions
    __shared__ int   lens[2];

    const int tid  = threadIdx.x;
    const int half = tid >> 9;           // 0 (waves 0-7) or 1 (waves 8-15)
    const int tA   = tid & 511;          // within-half thread id
    const int b    = (blockIdx.x << 1) | half;
    const int w    = tA >> 6;            // wave-in-half 0..7
    const int l6   = tid & 63;
    const int o    = l6 & 15;            // k-octet: k in [8o, 8o+8)
    const int jg   = (w << 2) | (l6 >> 4);  // j-group 0..31: j in [4jg, 4jg+4)
    const int len  = x_len[b];           // half-uniform

    const float* xb = x   + (size_t)b * Lc * Dc;
    const int*   tb = tag + (size_t)b * Lc;

    // swizzled E float-index: f(k) = k ^ (4*(k>>5))  (bijective)
    const int sw   = 4 * (o >> 2);
    const int i0   = (o << 3) ^ sw;          // elements 8o..8o+3
    const int i1   = ((o << 3) + 4) ^ sw;    // elements 8o+4..8o+7
    const int jw   = 4 * jg + (o & 3);       // this lane's output j (o<4 writes)
    const int widx = jw ^ (4 * (jw >> 5));   // swizzled write index
    const int jr   = (jw < Dc) ? jw : 0;     // clamped logit index

    // ---- constant weights: treg[g][c] = exp(trans[4jg+g, 8o+c]) ----
    // (identical for both halves: transitions are shared)
    float treg[4][8];
#pragma unroll
    for (int g = 0; g < 4; ++g) {
        const float4* tp = reinterpret_cast<const float4*>(trans + (4*jg + g) * Tc + 8*o);
        float4 t0 = tp[0], t1 = tp[1];
        treg[g][0] = FEXP2(t0.x * LOG2E); treg[g][1] = FEXP2(t0.y * LOG2E);
        treg[g][2] = FEXP2(t0.z * LOG2E); treg[g][3] = FEXP2(t0.w * LOG2E);
        treg[g][4] = FEXP2(t1.x * LOG2E); treg[g][5] = FEXP2(t1.y * LOG2E);
        treg[g][6] = FEXP2(t1.z * LOG2E); treg[g][7] = FEXP2(t1.w * LOG2E);
    }

    // ---- preload chunk 0; init E = delta(START=126); publish len ----
    {
        float4 q0 = make_float4(0.f, 0.f, 0.f, 0.f);
        if (tA < CHF / 4) q0 = *reinterpret_cast<const float4*>(xb + 4 * tA);
        if (tA < Tc) E[half][0][tA ^ (4 * (tA >> 5))] = (tA == Tc - 2) ? 1.0f : 0.0f;
        if (tA < CHF / 4) *reinterpret_cast<float4*>(&Lbuf[half][0][4 * tA]) = q0;
        if (tA == 0) lens[half] = len;
    }
    __syncthreads();
    const int lenmax = max(lens[0], lens[1]);

    float P    = (jw < Dc) ? FEXP2(Lbuf[half][0][jr] * LOG2E) : 0.0f;  // step-0 emission
    int   Mint = 0;                       // exact base-2 shift accumulator
    float4 stq = make_float4(0.f, 0.f, 0.f, 0.f);                      // staging regs

    // ---- forward recursion: one raw barrier/step, both halves in lockstep ----
    for (int l = 0; l < lenmax; ++l) {
        if (l < len) {
            const int p   = l & 1;
            const int sub = l & (CH - 1);
            const int cb  = (l >> 4) & 1;

            // staging (half-uniform): issue loads at sub==0 for chunk c+1;
            // ds_write them at sub==8 (counted vmcnt wait lands there; raw
            // barriers don't drain vmcnt, so HBM latency stays covered)
            if (sub == 0) {
                const int c1 = (l >> 4) + 1;
                if (c1 < NCH && tA < CHF / 4)
                    stq = *reinterpret_cast<const float4*>(xb + (size_t)c1 * CHF + 4 * tA);
            } else if (sub == 8) {
                const int c1 = (l >> 4) + 1;
                if (c1 < NCH && tA < CHF / 4)
                    *reinterpret_cast<float4*>(&Lbuf[half][cb ^ 1][4 * tA]) = stq;
            }

            // E operands: 2x ds_read_b128 (swizzled)
            const float* Ep = E[half][p];
            float4 ea  = *reinterpret_cast<const float4*>(Ep + i0);
            float4 eb4 = *reinterpret_cast<const float4*>(Ep + i1);

            // prefetch next-step logit (off the post-reduce chain)
            const int ln = (l + 1 < len) ? (l + 1) : l;
            const float lv = Lbuf[half][(ln >> 4) & 1][(ln & (CH - 1)) * Dc + jr];

            // 4 outputs x 8 inputs = 32 FMA
            float a0 = treg[0][0] * ea.x, a1 = treg[1][0] * ea.x,
                  a2 = treg[2][0] * ea.x, a3 = treg[3][0] * ea.x;
            a0 = fmaf(treg[0][1], ea.y, a0);  a1 = fmaf(treg[1][1], ea.y, a1);
            a2 = fmaf(treg[2][1], ea.y, a2);  a3 = fmaf(treg[3][1], ea.y, a3);
            a0 = fmaf(treg[0][2], ea.z, a0);  a1 = fmaf(treg[1][2], ea.z, a1);
            a2 = fmaf(treg[2][2], ea.z, a2);  a3 = fmaf(treg[3][2], ea.z, a3);
            a0 = fmaf(treg[0][3], ea.w, a0);  a1 = fmaf(treg[1][3], ea.w, a1);
            a2 = fmaf(treg[2][3], ea.w, a2);  a3 = fmaf(treg[3][3], ea.w, a3);
            a0 = fmaf(treg[0][4], eb4.x, a0); a1 = fmaf(treg[1][4], eb4.x, a1);
            a2 = fmaf(treg[2][4], eb4.x, a2); a3 = fmaf(treg[3][4], eb4.x, a3);
            a0 = fmaf(treg[0][5], eb4.y, a0); a1 = fmaf(treg[1][5], eb4.y, a1);
            a2 = fmaf(treg[2][5], eb4.y, a2); a3 = fmaf(treg[3][5], eb4.y, a3);
            a0 = fmaf(treg[0][6], eb4.z, a0); a1 = fmaf(treg[1][6], eb4.z, a1);
            a2 = fmaf(treg[2][6], eb4.z, a2); a3 = fmaf(treg[3][6], eb4.z, a3);
            a0 = fmaf(treg[0][7], eb4.w, a0); a1 = fmaf(treg[1][7], eb4.w, a1);
            a2 = fmaf(treg[2][7], eb4.w, a2); a3 = fmaf(treg[3][7], eb4.w, a3);

            // ring-reduce over the 16-lane row: every lane gets full sums
            a0 += ROR1(a0); a1 += ROR1(a1); a2 += ROR1(a2); a3 += ROR1(a3);
            a0 += ROR2(a0); a1 += ROR2(a1); a2 += ROR2(a2); a3 += ROR2(a3);
            a0 += ROR4(a0); a1 += ROR4(a1); a2 += ROR4(a2); a3 += ROR4(a3);
            a0 += ROR8(a0); a1 += ROR8(a1); a2 += ROR8(a2); a3 += ROR8(a3);

            // rebase every 4th step (power-of-2 scale is exact; worst-case
            // growth ~2^21/step keeps 4-step runs inside fp32 range)
            float R;
            if ((l & 3) == 3) {
                float mx = fmaxf(ea.z, eb4.z);           // samples k==2 mod 4
                mx = fmaxf(mx, ROR1(mx)); mx = fmaxf(mx, ROR2(mx));
                mx = fmaxf(mx, ROR4(mx)); mx = fmaxf(mx, ROR8(mx));
                int ebq = (__float_as_int(mx) >> 23) & 0xFF;
                R = __int_as_float((254 - ebq) << 23);   // 2^(127-ebq)
                Mint += ebq - 127;
            } else {
                R = 1.0f;
            }

            // lane o<4 owns j = 4jg+o: select its sum, apply emission + rebase
            float sel = a0;
            sel = (o == 1) ? a1 : sel;
            sel = (o == 2) ? a2 : sel;
            sel = (o == 3) ? a3 : sel;
            float eout = sel * P * R;
            if (o < 4) E[half][p ^ 1][widx] = eout;

            // next-step emission factor (lv already in flight)
            P = (jw < Dc) ? FEXP2(lv * LOG2E) : 0.0f;
        }
        STEP_BARRIER();
    }
    const int pf = len & 1;              // final E buffer for this half

    // ---- score: emission + pairwise transitions (cooperative over l) ----
    float acc = 0.f;
    for (int l = tA; l < len; l += 512) {
        int   tg = tb[l];
        float tr = (l == 0) ? trans[tg * Tc + (Tc - 2)]
                            : trans[tg * Tc + tb[l - 1]];
        acc += xb[(size_t)l * Dc + tg] + tr;
    }
#pragma unroll
    for (int off = 1; off < 64; off <<= 1)
        acc += __shfl_xor(acc, off, 64);
    if (l6 == 0) red[half][w] = acc;

    // ---- partition = ln2 * (Mint + log2(sum_k exp(t_stop_k) * E_k)) ----
    if (w == 0) {                        // first wave of each half
        int k0i = l6, k1i = 64 + l6;
        float p0 = FEXP2(trans[(Tc-1) * Tc + k0i] * LOG2E) * E[half][pf][k0i ^ (4 * (k0i >> 5))];
        float p1 = FEXP2(trans[(Tc-1) * Tc + k1i] * LOG2E) * E[half][pf][k1i ^ (4 * (k1i >> 5))];
        float ps = p0 + p1;
#pragma unroll
        for (int off = 1; off < 64; off <<= 1)
            ps += __shfl_xor(ps, off, 64);
        if (l6 == 0) red[half][8] = LN2 * ((float)Mint + FLOG2(ps));
    }
    __syncthreads();

    if (tA == 0) {
        float sc = trans[(Tc-1) * Tc + tb[len - 1]];   // STOP transition
#pragma unroll
        for (int i = 0; i < 8; ++i) sc += red[half][i];
        out[b] = sc - red[half][8];
    }
}

extern "C" void kernel_launch(void* const* d_in, const int* in_sizes, int n_in,
                              void* d_out, int out_size, void* d_ws, size_t ws_size,
                              hipStream_t stream) {
    const float* x     = (const float*)d_in[0];
    const float* trans = (const float*)d_in[1];
    // d_in[2] = x_mask (redundant with x_len)
    const int*   x_len = (const int*)d_in[3];
    const int*   tag   = (const int*)d_in[4];
    float*       out   = (float*)d_out;

    crf_fwd_kernel<<<Bc / 2, 1024, 0, stream>>>(x, trans, x_len, tag, out);
}

// Round 3
// 586.414 us; speedup vs baseline: 1.3574x; 1.3574x over previous
//
#include <hip/hip_runtime.h>

// CRF log-likelihood. B=256, L=1024, D=126, T=128. One block/batch, 256 thr.
// R6: solo-step shrink (R5 lesson: wall time = 1024 x solo step; packing
// can't help). 4 waves/block (1/SIMD): thread = 4 outputs (j) x 16 inputs
// (k), 4x ds_read_b128 for E, 3-stage DPP reduce (quad xor1, xor2,
// row_half_mirror) over the 8-lane k-group. E stored quad-permuted
// (F(k)=4*Q(k>>2)+(k&3), Q(q)=q^((q>>3)&3)): reads AND writes provably
// bank-conflict-free (R4's XOR swizzle was 2-way+, 9.2M conflicts).
// Rebase every 4th step; raw lgkmcnt(0)+s_barrier (no vmcnt drain) so
// staged global loads (issued sub==0, LDS-written sub==8) stay in flight.

#define LOG2E   1.4426950408889634f
#define LN2     0.6931471805599453f

constexpr int Bc = 256, Lc = 1024, Dc = 126, Tc = 128;
constexpr int CH = 16, CHF = CH * Dc;       // 2016 floats per chunk
constexpr int NCH = Lc / CH;                // 64 chunks

#if __has_builtin(__builtin_amdgcn_exp2f)
#define FEXP2(x) __builtin_amdgcn_exp2f(x)
#else
#define FEXP2(x) exp2f(x)
#endif
#if __has_builtin(__builtin_amdgcn_logf)
#define FLOG2(x) __builtin_amdgcn_logf(x)
#else
#define FLOG2(x) log2f(x)
#endif

// DPP lane exchange within the 8-lane k-group (lanes l6&7):
//  QX1: quad_perm {1,0,3,2} = 0xB1 (xor 1)
//  QX2: quad_perm {2,3,0,1} = 0x4E (xor 2)
//  HMIR: row_half_mirror = 0x141 (i -> 7-i within each 8; crosses the two
//        quads of the 8-group; valid 3rd reduce stage once quads are uniform)
#if __has_builtin(__builtin_amdgcn_mov_dpp)
#define DPPF(x, ctrl) __int_as_float(__builtin_amdgcn_mov_dpp(__float_as_int(x), (ctrl), 0xF, 0xF, true))
#define QX1(x)  DPPF(x, 0xB1)
#define QX2(x)  DPPF(x, 0x4E)
#define HMIR(x) DPPF(x, 0x141)
#else
#define QX1(x)  __shfl_xor((x), 1, 64)
#define QX2(x)  __shfl_xor((x), 2, 64)
#define HMIR(x) __shfl_xor((x), 4, 64)
#endif

#define STEP_BARRIER() asm volatile("s_waitcnt lgkmcnt(0)\n\ts_barrier" ::: "memory")

// quad-permuted E storage: element k lives at float index F(k).
__device__ __forceinline__ int Fmap(int k) {
    int q = k >> 2;
    q ^= (q >> 3) & 3;
    return 4 * q + (k & 3);
}

__global__ __launch_bounds__(256, 1) void crf_fwd_kernel(
    const float* __restrict__ x,      // [B, L, D]
    const float* __restrict__ trans,  // [T, T] row-major
    const int*   __restrict__ x_len,  // [B]
    const int*   __restrict__ tag,    // [B, L]
    float*       __restrict__ out)    // [B]
{
    __shared__ __align__(16) float E[2][Tc];       // rebased exp(alpha), dbuf, quad-permuted
    __shared__ __align__(16) float Lbuf[2][CHF];   // staged logits, dbuf, linear
    __shared__ float red[12];                      // epilogue reductions

    const int b   = blockIdx.x;
    const int tid = threadIdx.x;
    const int w   = tid >> 6;            // wave 0..3
    const int l6  = tid & 63;
    const int kg  = l6 & 7;              // k-group: k in [16kg, 16kg+16)
    const int jg  = (w << 3) | (l6 >> 3);// j-group 0..31: j in [4jg, 4jg+4)
    const int len = x_len[b];            // block-uniform

    const float* xb = x   + (size_t)b * Lc * Dc;
    const int*   tb = tag + (size_t)b * Lc;

    // E read offsets: quad q = 4kg+r, conflict-free by construction
    int f0, f1, f2, f3;
    {
        int q0 = 4 * kg + 0; q0 ^= (q0 >> 3) & 3; f0 = 4 * q0;
        int q1 = 4 * kg + 1; q1 ^= (q1 >> 3) & 3; f1 = 4 * q1;
        int q2 = 4 * kg + 2; q2 ^= (q2 >> 3) & 3; f2 = 4 * q2;
        int q3 = 4 * kg + 3; q3 ^= (q3 >> 3) & 3; f3 = 4 * q3;
    }
    const int  jw   = 4 * jg + (kg & 3); // this lane's output j (kg<4 writes)
    const int  widx = Fmap(jw);          // permuted write index
    const int  jr   = (jw < Dc) ? jw : 0;// clamped logit index
    const bool wr   = (kg < 4);

    // ---- constant weights: treg[g][c] = exp(trans[4jg+g, 16kg+c]) ----
    float treg[4][16];
#pragma unroll
    for (int g = 0; g < 4; ++g) {
        const float4* tp = reinterpret_cast<const float4*>(trans + (4*jg + g) * Tc + 16*kg);
#pragma unroll
        for (int c4 = 0; c4 < 4; ++c4) {
            float4 t4 = tp[c4];
            treg[g][4*c4+0] = FEXP2(t4.x * LOG2E);
            treg[g][4*c4+1] = FEXP2(t4.y * LOG2E);
            treg[g][4*c4+2] = FEXP2(t4.z * LOG2E);
            treg[g][4*c4+3] = FEXP2(t4.w * LOG2E);
        }
    }

    // ---- preload chunk 0; init E = delta(START=126) ----
    {
        float4 q0 = *reinterpret_cast<const float4*>(xb + 4 * tid);
        float4 q1 = make_float4(0.f, 0.f, 0.f, 0.f);
        if (tid < (CHF/4 - 256)) q1 = *reinterpret_cast<const float4*>(xb + 1024 + 4 * tid);
        if (tid < Tc) E[0][Fmap(tid)] = (tid == Tc - 2) ? 1.0f : 0.0f;
        *reinterpret_cast<float4*>(&Lbuf[0][4 * tid]) = q0;
        if (tid < (CHF/4 - 256)) *reinterpret_cast<float4*>(&Lbuf[0][1024 + 4 * tid]) = q1;
    }
    __syncthreads();

    float P    = (jw < Dc) ? FEXP2(Lbuf[0][jr] * LOG2E) : 0.0f;  // step-0 emission
    int   Mint = 0;                       // exact base-2 shift accumulator
    float4 s0q = make_float4(0.f,0.f,0.f,0.f), s1q = make_float4(0.f,0.f,0.f,0.f);

    // ---- forward recursion: one raw 4-wave barrier per step ----
    for (int l = 0; l < len; ++l) {
        const int p   = l & 1;
        const int sub = l & (CH - 1);
        const int cb  = (l >> 4) & 1;

        // staging (block-uniform): issue loads at sub==0 for chunk c+1;
        // ds_write them at sub==8 (counted vmcnt wait lands there; raw
        // barriers don't drain vmcnt, so HBM latency stays covered)
        if (sub == 0) {
            const int c1 = (l >> 4) + 1;
            if (c1 < NCH) {
                const float* src = xb + (size_t)c1 * CHF;
                s0q = *reinterpret_cast<const float4*>(src + 4 * tid);
                if (tid < (CHF/4 - 256))
                    s1q = *reinterpret_cast<const float4*>(src + 1024 + 4 * tid);
            }
        } else if (sub == 8) {
            const int c1 = (l >> 4) + 1;
            if (c1 < NCH) {
                *reinterpret_cast<float4*>(&Lbuf[cb ^ 1][4 * tid]) = s0q;
                if (tid < (CHF/4 - 256))
                    *reinterpret_cast<float4*>(&Lbuf[cb ^ 1][1024 + 4 * tid]) = s1q;
            }
        }

        // E operands: 4x ds_read_b128, conflict-free (quad-permuted layout)
        const float* Ep = E[p];
        float4 e0 = *reinterpret_cast<const float4*>(Ep + f0);
        float4 e1 = *reinterpret_cast<const float4*>(Ep + f1);
        float4 e2 = *reinterpret_cast<const float4*>(Ep + f2);
        float4 e3 = *reinterpret_cast<const float4*>(Ep + f3);

        // prefetch next-step logit (off the post-reduce chain)
        const int ln = (l + 1 < len) ? (l + 1) : l;
        const float lv = Lbuf[(ln >> 4) & 1][(ln & (CH - 1)) * Dc + jr];

        // 4 outputs x 16 inputs = 64 FMA, split lo/hi to halve dep chains
        float a0, a1, a2, a3;
        {
            float l0 = treg[0][0]*e0.x, l1 = treg[1][0]*e0.x, l2 = treg[2][0]*e0.x, l3 = treg[3][0]*e0.x;
            float h0 = treg[0][8]*e2.x, h1 = treg[1][8]*e2.x, h2 = treg[2][8]*e2.x, h3 = treg[3][8]*e2.x;
            l0=fmaf(treg[0][1],e0.y,l0); l1=fmaf(treg[1][1],e0.y,l1); l2=fmaf(treg[2][1],e0.y,l2); l3=fmaf(treg[3][1],e0.y,l3);
            h0=fmaf(treg[0][9],e2.y,h0); h1=fmaf(treg[1][9],e2.y,h1); h2=fmaf(treg[2][9],e2.y,h2); h3=fmaf(treg[3][9],e2.y,h3);
            l0=fmaf(treg[0][2],e0.z,l0); l1=fmaf(treg[1][2],e0.z,l1); l2=fmaf(treg[2][2],e0.z,l2); l3=fmaf(treg[3][2],e0.z,l3);
            h0=fmaf(treg[0][10],e2.z,h0); h1=fmaf(treg[1][10],e2.z,h1); h2=fmaf(treg[2][10],e2.z,h2); h3=fmaf(treg[3][10],e2.z,h3);
            l0=fmaf(treg[0][3],e0.w,l0); l1=fmaf(treg[1][3],e0.w,l1); l2=fmaf(treg[2][3],e0.w,l2); l3=fmaf(treg[3][3],e0.w,l3);
            h0=fmaf(treg[0][11],e2.w,h0); h1=fmaf(treg[1][11],e2.w,h1); h2=fmaf(treg[2][11],e2.w,h2); h3=fmaf(treg[3][11],e2.w,h3);
            l0=fmaf(treg[0][4],e1.x,l0); l1=fmaf(treg[1][4],e1.x,l1); l2=fmaf(treg[2][4],e1.x,l2); l3=fmaf(treg[3][4],e1.x,l3);
            h0=fmaf(treg[0][12],e3.x,h0); h1=fmaf(treg[1][12],e3.x,h1); h2=fmaf(treg[2][12],e3.x,h2); h3=fmaf(treg[3][12],e3.x,h3);
            l0=fmaf(treg[0][5],e1.y,l0); l1=fmaf(treg[1][5],e1.y,l1); l2=fmaf(treg[2][5],e1.y,l2); l3=fmaf(treg[3][5],e1.y,l3);
            h0=fmaf(treg[0][13],e3.y,h0); h1=fmaf(treg[1][13],e3.y,h1); h2=fmaf(treg[2][13],e3.y,h2); h3=fmaf(treg[3][13],e3.y,h3);
            l0=fmaf(treg[0][6],e1.z,l0); l1=fmaf(treg[1][6],e1.z,l1); l2=fmaf(treg[2][6],e1.z,l2); l3=fmaf(treg[3][6],e1.z,l3);
            h0=fmaf(treg[0][14],e3.z,h0); h1=fmaf(treg[1][14],e3.z,h1); h2=fmaf(treg[2][14],e3.z,h2); h3=fmaf(treg[3][14],e3.z,h3);
            l0=fmaf(treg[0][7],e1.w,l0); l1=fmaf(treg[1][7],e1.w,l1); l2=fmaf(treg[2][7],e1.w,l2); l3=fmaf(treg[3][7],e1.w,l3);
            h0=fmaf(treg[0][15],e3.w,h0); h1=fmaf(treg[1][15],e3.w,h1); h2=fmaf(treg[2][15],e3.w,h2); h3=fmaf(treg[3][15],e3.w,h3);
            a0 = l0 + h0; a1 = l1 + h1; a2 = l2 + h2; a3 = l3 + h3;
        }

        // reduce over the 8-lane k-group: every lane gets full sums
        a0 += QX1(a0);  a1 += QX1(a1);  a2 += QX1(a2);  a3 += QX1(a3);
        a0 += QX2(a0);  a1 += QX2(a1);  a2 += QX2(a2);  a3 += QX2(a3);
        a0 += HMIR(a0); a1 += HMIR(a1); a2 += HMIR(a2); a3 += HMIR(a3);

        // rebase every 4th step (power-of-2 scale is exact; samples k==2 mod 4)
        float R;
        if ((l & 3) == 3) {
            float mx = fmaxf(fmaxf(e0.z, e1.z), fmaxf(e2.z, e3.z));
            mx = fmaxf(mx, QX1(mx)); mx = fmaxf(mx, QX2(mx)); mx = fmaxf(mx, HMIR(mx));
            int ebq = (__float_as_int(mx) >> 23) & 0xFF;
            R = __int_as_float((254 - ebq) << 23);   // 2^(127-ebq)
            Mint += ebq - 127;
        } else {
            R = 1.0f;
        }

        // lane kg<4 owns j = 4jg+kg: select its sum, apply emission + rebase
        float sel = a0;
        sel = (kg == 1) ? a1 : sel;
        sel = (kg == 2) ? a2 : sel;
        sel = (kg == 3) ? a3 : sel;
        float eout = sel * P * R;
        if (wr) E[p ^ 1][widx] = eout;

        // next-step emission factor (lv already in flight)
        P = (jw < Dc) ? FEXP2(lv * LOG2E) : 0.0f;

        STEP_BARRIER();
    }
    const int pf = len & 1;              // final E buffer

    // ---- score: emission + pairwise transitions (cooperative over l) ----
    float acc = 0.f;
    for (int l = tid; l < len; l += 256) {
        int   tg = tb[l];
        float tr = (l == 0) ? trans[tg * Tc + (Tc - 2)]
                            : trans[tg * Tc + tb[l - 1]];
        acc += xb[(size_t)l * Dc + tg] + tr;
    }
#pragma unroll
    for (int off = 1; off < 64; off <<= 1)
        acc += __shfl_xor(acc, off, 64);
    if (l6 == 0) red[w] = acc;

    // ---- partition = ln2 * (Mint + log2(sum_k exp(t_stop_k) * E_k)) ----
    if (w == 0) {
        int k0i = l6, k1i = 64 + l6;
        float p0 = FEXP2(trans[(Tc-1) * Tc + k0i] * LOG2E) * E[pf][Fmap(k0i)];
        float p1 = FEXP2(trans[(Tc-1) * Tc + k1i] * LOG2E) * E[pf][Fmap(k1i)];
        float ps = p0 + p1;
#pragma unroll
        for (int off = 1; off < 64; off <<= 1)
            ps += __shfl_xor(ps, off, 64);
        if (l6 == 0) red[8] = LN2 * ((float)Mint + FLOG2(ps));
    }
    __syncthreads();

    if (tid == 0) {
        float sc = trans[(Tc-1) * Tc + tb[len - 1]];   // STOP transition
#pragma unroll
        for (int i = 0; i < 4; ++i) sc += red[i];
        out[b] = sc - red[8];
    }
}

extern "C" void kernel_launch(void* const* d_in, const int* in_sizes, int n_in,
                              void* d_out, int out_size, void* d_ws, size_t ws_size,
                              hipStream_t stream) {
    const float* x     = (const float*)d_in[0];
    const float* trans = (const float*)d_in[1];
    // d_in[2] = x_mask (redundant with x_len)
    const int*   x_len = (const int*)d_in[3];
    const int*   tag   = (const int*)d_in[4];
    float*       out   = (float*)d_out;

    crf_fwd_kernel<<<Bc, 256, 0, stream>>>(x, trans, x_len, tag, out);
}